// Round 6
// baseline (177.703 us; speedup 1.0000x reference)
//
#include <hip/hip_runtime.h>
#include <hip/hip_bf16.h>

// GeodesicLoss: reference's velocity starts at exactly zero, so
// acc = -einsum(Gamma, v, v) == 0 every step and traj == outputs identically.
// Answer = mean_b ||outputs[b] - targets[b]||_2, B=524288, D=32.
// christoffel_symbols (d_in[2]) is mathematically dead.
//
// R1-R5 post-mortem: all variants execute 512 wave-loads/CU and land at
// 205-293 cyc/wave-load, independent of ILP (R5 forced 8-deep DMA), TLP
// (23-59% occ), or staging. Limiter is downstream of issue. The only
// pattern with a 6.29 TB/s pedigree on this machine is the pure float4
// copy loop (no cross-lane, no barrier, persistent grid-stride).
// R6: clone it. Pass 1 = copy-like: load o4/g4, 7 VALU, store 1 bf16
// partial per float4 (8.4 MB writes, 6% overhead). No shuffles/LDS.
// Pass 2 = one thread per row: one 16B load of 8 bf16 partials, sum,
// sqrt, wave-reduce, 1 atomic/block.

static constexpr int B_ROWS  = 524288;            // D=32 -> 8 float4/row
static constexpr int NUM_F4  = B_ROWS * 8;        // 4,194,304 float4/array
static constexpr int P1_BLK  = 256;
static constexpr int P1_NBLK = 2048;              // 8 blocks/CU resident
static constexpr int P1_THREADS = P1_BLK * P1_NBLK;   // 524288
static constexpr int P1_ITER = NUM_F4 / P1_THREADS;   // 8

typedef __attribute__((ext_vector_type(8))) unsigned short ushort8;

__global__ __launch_bounds__(P1_BLK) void geodesic_pass1(
    const float4* __restrict__ o4,
    const float4* __restrict__ t4,
    __hip_bfloat16* __restrict__ partial)
{
    const int gtid = blockIdx.x * P1_BLK + threadIdx.x;
#pragma unroll
    for (int i = 0; i < P1_ITER; ++i) {
        const int idx = i * P1_THREADS + gtid;    // contiguous sweep per iter
        float4 o = o4[idx];
        float4 g = t4[idx];
        float dx = o.x - g.x;
        float dy = o.y - g.y;
        float dz = o.z - g.z;
        float dw = o.w - g.w;
        float p  = dx * dx + dy * dy + dz * dz + dw * dw;
        partial[idx] = __float2bfloat16(p);       // coalesced 2 B/lane store
    }
}

static constexpr int P2_BLK  = 256;
static constexpr int P2_NBLK = B_ROWS / P2_BLK;   // 2048

__global__ __launch_bounds__(P2_BLK) void geodesic_pass2(
    const ushort8* __restrict__ partial8,         // 8 bf16 = one row's partials
    float* __restrict__ out)
{
    const int row = blockIdx.x * P2_BLK + threadIdx.x;
    ushort8 p = partial8[row];                    // 16 B/lane, coalesced

    float ss = 0.0f;
#pragma unroll
    for (int j = 0; j < 8; ++j) {
        __hip_bfloat16_raw r; r.x = p[j];
        ss += (float)__hip_bfloat16(r);
    }
    float d = sqrtf(ss);

    d += __shfl_xor(d, 1);
    d += __shfl_xor(d, 2);
    d += __shfl_xor(d, 4);
    d += __shfl_xor(d, 8);
    d += __shfl_xor(d, 16);
    d += __shfl_xor(d, 32);

    __shared__ float sm[4];
    if ((threadIdx.x & 63) == 0) sm[threadIdx.x >> 6] = d;
    __syncthreads();
    if (threadIdx.x == 0) {
        atomicAdd(out, (sm[0] + sm[1] + sm[2] + sm[3]) * (1.0f / (float)B_ROWS));
    }
}

extern "C" void kernel_launch(void* const* d_in, const int* in_sizes, int n_in,
                              void* d_out, int out_size, void* d_ws, size_t ws_size,
                              hipStream_t stream) {
    const float4* outputs = (const float4*)d_in[0];
    const float4* targets = (const float4*)d_in[1];
    // d_in[2] (christoffel_symbols) unused: velocity is identically zero.
    float* out = (float*)d_out;
    __hip_bfloat16* partial = (__hip_bfloat16*)d_ws;   // 4M bf16 = 8.4 MB

    // d_out is re-poisoned to 0xAA before every timed launch; zero it.
    hipMemsetAsync(out, 0, sizeof(float), stream);

    geodesic_pass1<<<dim3(P1_NBLK), dim3(P1_BLK), 0, stream>>>(
        outputs, targets, partial);
    geodesic_pass2<<<dim3(P2_NBLK), dim3(P2_BLK), 0, stream>>>(
        (const ushort8*)partial, out);
}

// Round 7
// 151.354 us; speedup vs baseline: 1.1741x; 1.1741x over previous
//
#include <hip/hip_runtime.h>

// GeodesicLoss: reference's velocity starts at exactly zero, so
// acc = -einsum(Gamma, v, v) == 0 every step and traj == outputs identically.
// Answer = mean_b ||outputs[b] - targets[b]||_2, B=524288, D=32.
// christoffel_symbols (d_in[2]) is mathematically dead.
//
// R1-R6 post-mortem: six structurally independent kernels (scalar grid-
// stride, unroll-ILP, LDS-transpose, pure TLP, async global_load_lds DMA,
// copy-clone stream) ALL converge at 2.0-3.05 TB/s read — external ceiling
// signature, not kernel structure. FETCH_SIZE pinned at exactly half the
// read set every round (LLC serves the other half).
// R7: clean A/B on the last untried knob — nontemporal loads (bypass cache
// allocation) on the otherwise-unchanged fastest structure (R3, 44 us).

static constexpr int B_ROWS       = 524288;
static constexpr int ROWS_PER_BLK = 256;                  // = blockDim.x
static constexpr int NUM_BLOCKS   = B_ROWS / ROWS_PER_BLK; // 2048
static constexpr int PAD          = 9;                    // LDS row stride (floats)

typedef float f32x4 __attribute__((ext_vector_type(4)));

__global__ __launch_bounds__(256) void geodesic_loss_kernel(
    const f32x4* __restrict__ o4,
    const f32x4* __restrict__ t4,
    float* __restrict__ out)
{
    __shared__ float part[ROWS_PER_BLK * PAD];            // 9216 B

    const int t    = threadIdx.x;
    const int base = blockIdx.x * (ROWS_PER_BLK * 8);     // float4 index

    // 16 independent, perfectly coalesced NONTEMPORAL loads
    // (global_load_dwordx4 ... nt — no cache allocation).
    f32x4 o[8], g[8];
#pragma unroll
    for (int k = 0; k < 8; ++k)
        o[k] = __builtin_nontemporal_load(o4 + base + k * 256 + t);
#pragma unroll
    for (int k = 0; k < 8; ++k)
        g[k] = __builtin_nontemporal_load(t4 + base + k * 256 + t);

    // Per-float4 squared-diff partials -> LDS (row-major, pad 9).
    const int l8 = t & 7;
#pragma unroll
    for (int k = 0; k < 8; ++k) {
        float dx = o[k].x - g[k].x;
        float dy = o[k].y - g[k].y;
        float dz = o[k].z - g[k].z;
        float dw = o[k].w - g[k].w;
        float p  = dx * dx + dy * dy + dz * dz + dw * dw;
        const int rl = (k * 256 + t) >> 3;                // local row 0..255
        part[rl * PAD + l8] = p;
    }
    __syncthreads();

    // Thread t owns local row t: sum its 8 partials, sqrt.
    float ss = 0.0f;
#pragma unroll
    for (int j = 0; j < 8; ++j) ss += part[t * PAD + j];
    float d = sqrtf(ss);

    // One wave reduce per thread (amortized over 8 rows of work).
    d += __shfl_xor(d, 1);
    d += __shfl_xor(d, 2);
    d += __shfl_xor(d, 4);
    d += __shfl_xor(d, 8);
    d += __shfl_xor(d, 16);
    d += __shfl_xor(d, 32);

    __shared__ float sm[4];
    const int wave = t >> 6;
    const int lane = t & 63;
    if (lane == 0) sm[wave] = d;
    __syncthreads();
    if (t == 0) {
        atomicAdd(out, (sm[0] + sm[1] + sm[2] + sm[3]) * (1.0f / (float)B_ROWS));
    }
}

extern "C" void kernel_launch(void* const* d_in, const int* in_sizes, int n_in,
                              void* d_out, int out_size, void* d_ws, size_t ws_size,
                              hipStream_t stream) {
    const f32x4* outputs = (const f32x4*)d_in[0];
    const f32x4* targets = (const f32x4*)d_in[1];
    // d_in[2] (christoffel_symbols) unused: velocity is identically zero.
    float* out = (float*)d_out;

    // d_out is re-poisoned to 0xAA before every timed launch; zero it.
    hipMemsetAsync(out, 0, sizeof(float), stream);

    geodesic_loss_kernel<<<dim3(NUM_BLOCKS), dim3(256), 0, stream>>>(
        outputs, targets, out);
}